// Round 6
// baseline (241.152 us; speedup 1.0000x reference)
//
#include <hip/hip_runtime.h>
#include <hip/hip_bf16.h>

// Restormer-style channel attention (MDTA). b=4, c=192, h=w=128 (n=16384),
// heads=4, ch=48. I/O fp32 (runtime-detected, bf16 tolerated).
//
// Launches:
//   k_pre:       weights -> canonical bf16, zero ssq/ssk/S
//   k_conv:      fused q|k|v conv1x1 MFMA -> Yall[proj][b][c][n].
//                NO transpose, NO LDS: A-frags direct from X[b][c][p].
//                Grid (128 px-tiles, 3 proj, 4 b) = 1536 blocks: occupancy
//                was grid-capped at 2 blocks/CU (17.7%) with 9 serial
//                d-tiles; splitting d by proj -> 6 blocks/CU, 3x A-frag
//                re-reads are same-XCD L2 hits (id deltas 128/384 = 0 mod 8).
//   k_dwconv:    fused q|k|v depthwise 3x3 — LDS-free, deep-prefetch
//   k_attn:      S = Q.K^T (MFMA over n, 16 chunks, atomics)
//   k_softmax:   fold L2 norms + temperature (normalize commutes with dot)
//   k_out:       out = attn . V (K=48 skinny GEMM, fp32 out)

typedef __attribute__((ext_vector_type(8))) short short8;
typedef __attribute__((ext_vector_type(4))) float f32x4;

#define NB 4
#define NC 192
#define NN 16384
#define CH 48
#define NWELEM 115780     // 3*36864 + 3*1728 + 4
#define NZERO 38400       // ssq(768) + ssk(768) + S(16*48*48) floats

__device__ inline unsigned short f2bf(float f) {
  union { float f; unsigned int u; } c; c.f = f;
  unsigned int r = c.u + 0x7FFF + ((c.u >> 16) & 1);   // RNE
  return (unsigned short)(r >> 16);
}
__device__ inline float bf2f(unsigned short u) {
  union { unsigned int u; float f; } c; c.u = ((unsigned int)u) << 16;
  return c.f;
}

// fp32 (true) vs bf16 (false), wave-uniform.
__device__ inline bool detect_f32(const unsigned short* x) {
  int l = threadIdx.x & 63;
  unsigned short u = x[2 * (l * 997 + 1)];
  int e = (u >> 7) & 0xFF;
  bool extreme = (e < 90) || (e > 165);
  return __popcll(__ballot(extreme)) >= 8;
}

// ------------------------------------------------------------ pre: convert + zero
__global__ __launch_bounds__(256) void k_pre(const unsigned short* __restrict__ x,
                                             const void* wq, const void* wk, const void* wv,
                                             const void* wqd, const void* wkd, const void* wvd,
                                             const void* temp,
                                             unsigned short* __restrict__ canon,
                                             float* __restrict__ zbase) {
  int blk = blockIdx.x;
  if (blk >= 453) {   // zero range
    int i = (blk - 453) * 256 + threadIdx.x;
    if (i < NZERO) zbase[i] = 0.f;
    return;
  }
  bool f32 = detect_f32(x);
  int i = blk * 256 + threadIdx.x;
  if (i >= NWELEM) return;
  const void* src; int off;
  if (i < 36864)       { src = wq;  off = i; }
  else if (i < 73728)  { src = wk;  off = i - 36864; }
  else if (i < 110592) { src = wv;  off = i - 73728; }
  else if (i < 112320) { src = wqd; off = i - 110592; }
  else if (i < 114048) { src = wkd; off = i - 112320; }
  else if (i < 115776) { src = wvd; off = i - 114048; }
  else                 { src = temp; off = i - 115776; }
  canon[i] = f32 ? f2bf(((const float*)src)[off])
                 : ((const unsigned short*)src)[off];
}

// ------------------------------------------------------------ fused conv1x1 (MFMA)
// Yall[proj][b][d][p] = sum_c Wall[proj*192+d][c] * X[b][c][p]
// Block: 128-px tile x proj x b. Wave (wm,wn): 32d x 64p quadrant.
// A-frags read direct from X (lane=pixel coalesced, 8 c-rows per frag).
__global__ __launch_bounds__(256) void k_conv(const unsigned short* __restrict__ Wall,
                                              const unsigned short* __restrict__ X,
                                              unsigned short* __restrict__ Yall) {
  bool f32 = detect_f32(X);
  int b = blockIdx.z, proj = blockIdx.y, p0 = blockIdx.x * 128;
  int tid = threadIdx.x;
  int lane = tid & 63, w = tid >> 6;
  int wm = w & 1, wn = w >> 1;        // wave -> 32d x 64p quadrant
  int lrow = lane & 15, lq = lane >> 4;
  // preload this wave's A-frags for all 6 k-steps (reused 3x):
  // bf[ks][nt][j] = X[b][ks*32+lq*8+j][p0 + wn*64 + nt*16 + lrow]
  short8 bf[6][4];
  if (f32) {
    const float* Xf = (const float*)X;
#pragma unroll
    for (int ks = 0; ks < 6; ++ks)
#pragma unroll
      for (int nt = 0; nt < 4; ++nt) {
        int px = p0 + wn * 64 + nt * 16 + lrow;
        const float* xp = Xf + ((size_t)b * NC + ks * 32 + lq * 8) * NN + px;
        short8 v;
#pragma unroll
        for (int j = 0; j < 8; ++j) v[j] = (short)f2bf(xp[(size_t)j * NN]);
        bf[ks][nt] = v;
      }
  } else {
#pragma unroll
    for (int ks = 0; ks < 6; ++ks)
#pragma unroll
      for (int nt = 0; nt < 4; ++nt) {
        int px = p0 + wn * 64 + nt * 16 + lrow;
        const unsigned short* xp = X + ((size_t)b * NC + ks * 32 + lq * 8) * NN + px;
        short8 v;
#pragma unroll
        for (int j = 0; j < 8; ++j) v[j] = (short)xp[(size_t)j * NN];
        bf[ks][nt] = v;
      }
  }
  unsigned short* Yb = Yall + (((size_t)proj * NB + b) * NC) * NN;
#pragma unroll
  for (int dt = 0; dt < 3; ++dt) {    // 3 d-tiles of 64 within this proj
    int d0 = proj * 192 + dt * 64;
    f32x4 acc[2][4];
    for (int mt = 0; mt < 2; ++mt)
      for (int nt = 0; nt < 4; ++nt) acc[mt][nt] = (f32x4){0.f, 0.f, 0.f, 0.f};
    for (int ks = 0; ks < 6; ++ks) {
      int k = ks * 32 + lq * 8;
      short8 a[2];
      for (int mt = 0; mt < 2; ++mt)
        a[mt] = *(const short8*)(Wall + (size_t)(d0 + wm * 32 + mt * 16 + lrow) * NC + k);
      for (int mt = 0; mt < 2; ++mt)
        for (int nt = 0; nt < 4; ++nt)
          acc[mt][nt] = __builtin_amdgcn_mfma_f32_16x16x32_bf16(a[mt], bf[ks][nt], acc[mt][nt], 0, 0, 0);
    }
    int c0 = dt * 64;
    for (int mt = 0; mt < 2; ++mt)
      for (int nt = 0; nt < 4; ++nt)
        for (int r = 0; r < 4; ++r) {
          int c = c0 + wm * 32 + mt * 16 + lq * 4 + r;
          int p = p0 + wn * 64 + nt * 16 + lrow;
          Yb[(size_t)c * NN + p] = f2bf(acc[mt][nt][r]);
        }
  }
}

// ------------------------------------------------------------ fused dwconv3x3 (+ sumsq)
// Deep-prefetch, LDS-free, shfl-free. One block = one (proj,b,c) 128x128 image.
// Thread: 8-col chunk (ch) x 8-row group (rg). All 10 input rows (8 + 2 halo)
// issued as one raw-bf16 load burst at entry (one latency exposure per wave);
// halo columns come from direct 2B edge loads (same cache lines as the
// neighbor lanes' short8 -> L1 hits, no ds/shfl dependency chain).
__device__ inline void cvtrow(short8 raw, unsigned short lo, unsigned short hi,
                              float* dst) {
  dst[0] = bf2f(lo);
#pragma unroll
  for (int j = 0; j < 8; ++j) dst[j + 1] = bf2f((unsigned short)raw[j]);
  dst[9] = bf2f(hi);
}

__global__ __launch_bounds__(256) void k_dwconv(const unsigned short* __restrict__ Yall,
                                                const unsigned short* __restrict__ Wdall,
                                                unsigned short* __restrict__ Pq,
                                                unsigned short* __restrict__ Pk,
                                                unsigned short* __restrict__ Pv,
                                                float* __restrict__ ssq,
                                                float* __restrict__ ssk) {
  int y = blockIdx.x, b = blockIdx.y;
  int proj = y / NC, c = y % NC;
  int tid = threadIdx.x;
  int lane = tid & 63, ch = tid & 15, rg = tid >> 4;
  const unsigned short* base = Yall + (((size_t)proj * NB + b) * NC + c) * NN;
  unsigned short* P = (proj == 0 ? Pq : (proj == 1 ? Pk : Pv));
  float* ss = (proj == 0 ? ssq : (proj == 1 ? ssk : nullptr));
  int r0 = rg * 8;

  // ---- prefetch burst: all 10 raw rows (r0-1 .. r0+8), 30 loads in flight.
  short8 raw[10];
  unsigned short hl[10], hr[10];
#pragma unroll
  for (int i = 0; i < 10; ++i) {
    int gy = r0 - 1 + i;
    const unsigned short* rp = base + gy * 128 + ch * 8;
    if (gy >= 0 && gy < 128) {
      raw[i] = *(const short8*)rp;
      hl[i] = (ch > 0)  ? rp[-1] : (unsigned short)0;
      hr[i] = (ch < 15) ? rp[8]  : (unsigned short)0;
    } else {
      raw[i] = (short8){0, 0, 0, 0, 0, 0, 0, 0};
      hl[i] = 0;
      hr[i] = 0;
    }
  }

  float wk9[9];
#pragma unroll
  for (int i = 0; i < 9; ++i) wk9[i] = bf2f(Wdall[(proj * NC + c) * 9 + i]);

  float rows[3][10];   // rows[i%3] holds extended input row (r0-1+i)
  cvtrow(raw[0], hl[0], hr[0], rows[0]);
  cvtrow(raw[1], hl[1], hr[1], rows[1]);
  float ssacc = 0.f;
#pragma unroll
  for (int r = 0; r < 8; ++r) {
    cvtrow(raw[r + 2], hl[r + 2], hr[r + 2], rows[(r + 2) % 3]);
    float z[8];
#pragma unroll
    for (int j = 0; j < 8; ++j) z[j] = 0.f;
#pragma unroll
    for (int dy = 0; dy < 3; ++dy) {
      const float* f = rows[(r + dy) % 3];
      float w0 = wk9[dy * 3], w1 = wk9[dy * 3 + 1], w2 = wk9[dy * 3 + 2];
#pragma unroll
      for (int j = 0; j < 8; ++j) z[j] += w0 * f[j] + w1 * f[j + 1] + w2 * f[j + 2];
    }
    short8 sv;
#pragma unroll
    for (int j = 0; j < 8; ++j) { sv[j] = (short)f2bf(z[j]); ssacc += z[j] * z[j]; }
    *(short8*)(P + ((size_t)b * NC + c) * NN + (r0 + r) * 128 + ch * 8) = sv;
  }
  if (ss) {
    for (int off = 32; off; off >>= 1) ssacc += __shfl_down(ssacc, off);
    if (lane == 0) atomicAdd(&ss[b * NC + c], ssacc);
  }
}

// ------------------------------------------------------------ S = Q.K^T
__global__ __launch_bounds__(256) void k_attn(const unsigned short* __restrict__ Qp,
                                              const unsigned short* __restrict__ Kp,
                                              float* __restrict__ S) {
  __shared__ float Sred[CH * CH];
  int bh = blockIdx.y, chunk = blockIdx.x;
  int b = bh >> 2, h = bh & 3;
  int tid = threadIdx.x, lane = tid & 63, w = tid >> 6;
  int lrow = lane & 15, lq = lane >> 4;
  const unsigned short* Qb = Qp + ((size_t)b * NC + h * CH) * NN;
  const unsigned short* Kb = Kp + ((size_t)b * NC + h * CH) * NN;
  int nbase = chunk * 1024 + w * 256;
  f32x4 acc[3][3];
  for (int i = 0; i < 3; ++i)
    for (int j = 0; j < 3; ++j) acc[i][j] = (f32x4){0.f, 0.f, 0.f, 0.f};
  for (int ks = 0; ks < 8; ++ks) {
    int n = nbase + ks * 32 + lq * 8;
    short8 a[3], bb[3];
    for (int t = 0; t < 3; ++t) a[t]  = *(const short8*)(Qb + (size_t)(t * 16 + lrow) * NN + n);
    for (int t = 0; t < 3; ++t) bb[t] = *(const short8*)(Kb + (size_t)(t * 16 + lrow) * NN + n);
    for (int ti = 0; ti < 3; ++ti)
      for (int tj = 0; tj < 3; ++tj)
        acc[ti][tj] = __builtin_amdgcn_mfma_f32_16x16x32_bf16(a[ti], bb[tj], acc[ti][tj], 0, 0, 0);
  }
  for (int i = tid; i < CH * CH; i += 256) Sred[i] = 0.f;
  __syncthreads();
  for (int ti = 0; ti < 3; ++ti)
    for (int tj = 0; tj < 3; ++tj)
      for (int r = 0; r < 4; ++r) {
        int row = ti * 16 + lq * 4 + r, col = tj * 16 + lrow;
        atomicAdd(&Sred[row * CH + col], acc[ti][tj][r]);
      }
  __syncthreads();
  float* Sg = S + bh * (CH * CH);
  for (int i = tid; i < CH * CH; i += 256) atomicAdd(&Sg[i], Sred[i]);
}

// ------------------------------------------------------------ softmax (+ norms)
__global__ void k_softmax(const float* __restrict__ S, const float* __restrict__ ssq,
                          const float* __restrict__ ssk, const unsigned short* __restrict__ tempc,
                          float* __restrict__ AT) {   // AT[bh][j][i]
  int bh = blockIdx.x, b = bh >> 2, h = bh & 3;
  int i = threadIdx.x;
  if (i >= CH) return;
  float t = bf2f(tempc[h]);
  float rq = 1.f / fmaxf(sqrtf(ssq[b * NC + h * CH + i]), 1e-12f);
  const float* Srow = S + bh * (CH * CH) + i * CH;
  float l[CH];
  float m = -1e30f;
  for (int j = 0; j < CH; ++j) {
    float rk = 1.f / fmaxf(sqrtf(ssk[b * NC + h * CH + j]), 1e-12f);
    l[j] = Srow[j] * rq * rk * t;
    m = fmaxf(m, l[j]);
  }
  float s = 0.f;
  for (int j = 0; j < CH; ++j) { l[j] = __expf(l[j] - m); s += l[j]; }
  float inv = 1.f / s;
  for (int j = 0; j < CH; ++j) AT[bh * (CH * CH) + j * CH + i] = l[j] * inv;
}

// ------------------------------------------------------------ out = attn . V
__global__ __launch_bounds__(256) void k_out(const float* __restrict__ AT,
                                             const unsigned short* __restrict__ Vp,
                                             void* __restrict__ Out,
                                             const unsigned short* __restrict__ x) {
  bool f32 = detect_f32(x);
  int bh = blockIdx.y, b = bh >> 2, h = bh & 3;
  int p0 = (blockIdx.x * 256 + threadIdx.x) * 2;
  const float* A = AT + bh * (CH * CH);            // [j][i], block-uniform
  const unsigned short* Vb = Vp + ((size_t)b * NC + h * CH) * NN;
  float a1[CH], a2[CH];
  for (int i = 0; i < CH; ++i) { a1[i] = 0.f; a2[i] = 0.f; }
  for (int j = 0; j < CH; ++j) {
    unsigned int u = *(const unsigned int*)(Vb + (size_t)j * NN + p0);
    float v1 = bf2f((unsigned short)(u & 0xFFFF));
    float v2 = bf2f((unsigned short)(u >> 16));
    const float* Aj = A + j * CH;
    for (int i = 0; i < CH; ++i) {
      float a = Aj[i];
      a1[i] += a * v1;
      a2[i] += a * v2;
    }
  }
  size_t obase = ((size_t)b * NC + h * CH) * NN;
  if (f32) {
    float* Of = (float*)Out;
    for (int i = 0; i < CH; ++i)
      *(float2*)(Of + obase + (size_t)i * NN + p0) = make_float2(a1[i], a2[i]);
  } else {
    unsigned short* Ob = (unsigned short*)Out;
    for (int i = 0; i < CH; ++i) {
      unsigned int u = ((unsigned int)f2bf(a2[i]) << 16) | f2bf(a1[i]);
      *(unsigned int*)(Ob + obase + (size_t)i * NN + p0) = u;
    }
  }
}

// ------------------------------------------------------------ launch
extern "C" void kernel_launch(void* const* d_in, const int* in_sizes, int n_in,
                              void* d_out, int out_size, void* d_ws, size_t ws_size,
                              hipStream_t stream) {
  const unsigned short* x = (const unsigned short*)d_in[0];

  const size_t TEN = (size_t)NB * NC * NN;   // 12,582,912 elems
  unsigned short* bufA = (unsigned short*)d_ws;   // Q'
  unsigned short* bufB = bufA + TEN;              // K'
  unsigned short* bufV = bufB + TEN;              // V'
  unsigned short* Yall = bufV + TEN;              // 3 conv outputs (75.5 MB)
  float* ssq = (float*)(Yall + 3 * TEN);
  float* ssk = ssq + NB * NC;
  float* S   = ssk + NB * NC;
  float* AT  = S + 16 * CH * CH;
  unsigned short* canon = (unsigned short*)(AT + 16 * CH * CH);
  // ws total ~= 151 MB (< 268 MB)
  const unsigned short* Wall = canon;             // Wq|Wk|Wv = 576x192
  const unsigned short* Wdall = canon + 110592;   // wqd|wkd|wvd = 576x9
  const unsigned short* Tmp = canon + 115776;

  k_pre<<<453 + (NZERO + 255) / 256, 256, 0, stream>>>(
      x, d_in[1], d_in[3], d_in[5], d_in[2], d_in[4], d_in[6], d_in[7], canon, ssq);
  k_conv<<<dim3(NN / 128, 3, NB), 256, 0, stream>>>(Wall, x, Yall);
  k_dwconv<<<dim3(3 * NC, NB), 256, 0, stream>>>(Yall, Wdall, bufA, bufB, bufV, ssq, ssk);
  k_attn<<<dim3(16, 16), 256, 0, stream>>>(bufA, bufB, S);
  k_softmax<<<16, 64, 0, stream>>>(S, ssq, ssk, Tmp, AT);
  k_out<<<dim3(NN / 512, 16), 256, 0, stream>>>(AT, bufV, d_out, x);
}

// Round 7
// 231.968 us; speedup vs baseline: 1.0396x; 1.0396x over previous
//
#include <hip/hip_runtime.h>
#include <hip/hip_bf16.h>

// Restormer-style channel attention (MDTA). b=4, c=192, h=w=128 (n=16384),
// heads=4, ch=48. I/O fp32 (runtime-detected, bf16 tolerated).
//
// Launches:
//   k_pre:       weights -> canonical bf16, zero ssq/ssk/S
//   k_conv:      fused q|k|v conv1x1 MFMA -> Yall[proj][b][c][n].
//                In-kernel transpose-staging: X[b][c][p] (float4/ushort4
//                coalesced) -> f2bf -> LDS Xs[px][c] (LDP=200), then the
//                proven round-1 MFMA body (bf[6][4] ds_read_b128 preload,
//                9 d-tiles, 2 blocks/CU). No Xt tensor, no transpose kernel,
//                no 192-strided-dword A-gather.
//   k_dwconv:    fused q|k|v depthwise 3x3 — LDS-free, deep-prefetch
//   k_attn:      S = Q.K^T (MFMA over n, 16 chunks, atomics)
//   k_softmax:   fold L2 norms + temperature (normalize commutes with dot)
//   k_out:       out = attn . V (K=48 skinny GEMM, fp32 out)

typedef __attribute__((ext_vector_type(8))) short short8;
typedef __attribute__((ext_vector_type(4))) float f32x4;

#define NB 4
#define NC 192
#define NN 16384
#define CH 48
#define NWELEM 115780     // 3*36864 + 3*1728 + 4
#define NZERO 38400       // ssq(768) + ssk(768) + S(16*48*48) floats
#define LDP 200           // LDS px-row stride (elems)

__device__ inline unsigned short f2bf(float f) {
  union { float f; unsigned int u; } c; c.f = f;
  unsigned int r = c.u + 0x7FFF + ((c.u >> 16) & 1);   // RNE
  return (unsigned short)(r >> 16);
}
__device__ inline float bf2f(unsigned short u) {
  union { unsigned int u; float f; } c; c.u = ((unsigned int)u) << 16;
  return c.f;
}

// fp32 (true) vs bf16 (false), wave-uniform.
__device__ inline bool detect_f32(const unsigned short* x) {
  int l = threadIdx.x & 63;
  unsigned short u = x[2 * (l * 997 + 1)];
  int e = (u >> 7) & 0xFF;
  bool extreme = (e < 90) || (e > 165);
  return __popcll(__ballot(extreme)) >= 8;
}

// ------------------------------------------------------------ pre: convert + zero
__global__ __launch_bounds__(256) void k_pre(const unsigned short* __restrict__ x,
                                             const void* wq, const void* wk, const void* wv,
                                             const void* wqd, const void* wkd, const void* wvd,
                                             const void* temp,
                                             unsigned short* __restrict__ canon,
                                             float* __restrict__ zbase) {
  int blk = blockIdx.x;
  if (blk >= 453) {   // zero range
    int i = (blk - 453) * 256 + threadIdx.x;
    if (i < NZERO) zbase[i] = 0.f;
    return;
  }
  bool f32 = detect_f32(x);
  int i = blk * 256 + threadIdx.x;
  if (i >= NWELEM) return;
  const void* src; int off;
  if (i < 36864)       { src = wq;  off = i; }
  else if (i < 73728)  { src = wk;  off = i - 36864; }
  else if (i < 110592) { src = wv;  off = i - 73728; }
  else if (i < 112320) { src = wqd; off = i - 110592; }
  else if (i < 114048) { src = wkd; off = i - 112320; }
  else if (i < 115776) { src = wvd; off = i - 114048; }
  else                 { src = temp; off = i - 115776; }
  canon[i] = f32 ? f2bf(((const float*)src)[off])
                 : ((const unsigned short*)src)[off];
}

// ------------------------------------------------------------ fused conv1x1 (MFMA)
// Yall[proj][b][d][p] = sum_c Wall[proj*192+d][c] * X[b][c][p]
// Block: 128-px tile x b. Wave (wm,wn): 32d x 64p quadrant.
// Stage X tile -> LDS [px][c] (in-kernel transpose), then round-1 MFMA body.
__global__ __launch_bounds__(256) void k_conv(const unsigned short* __restrict__ Wall,
                                              const unsigned short* __restrict__ X,
                                              unsigned short* __restrict__ Yall) {
  __shared__ __align__(16) unsigned short Xs[128 * LDP];  // 51.2 KB
  bool f32 = detect_f32(X);
  int b = blockIdx.y, p0 = blockIdx.x * 128;
  int tid = threadIdx.x;
  // ---- stage: thread = 2 c-rows x 4 px per iter; 12 iters covers 192c x 128px.
  // Writes packed (c,c+1) pairs -> b32 at Xs[px*LDP + c] (c even -> 4B aligned).
  if (f32) {
    const float* Xf = (const float*)X + (size_t)b * NC * NN + p0;
    for (int it = 0; it < 12; ++it) {
      int idx = it * 256 + tid;
      int c = (idx >> 5) * 2, pq = idx & 31;
      float4 v0 = *(const float4*)(Xf + (size_t)c * NN + pq * 4);
      float4 v1 = *(const float4*)(Xf + (size_t)(c + 1) * NN + pq * 4);
#pragma unroll
      for (int j = 0; j < 4; ++j) {
        unsigned int u = ((unsigned int)f2bf((&v1.x)[j]) << 16) | f2bf((&v0.x)[j]);
        *(unsigned int*)(&Xs[(pq * 4 + j) * LDP + c]) = u;
      }
    }
  } else {
    const unsigned short* Xb = X + (size_t)b * NC * NN + p0;
    for (int it = 0; it < 12; ++it) {
      int idx = it * 256 + tid;
      int c = (idx >> 5) * 2, pq = idx & 31;
      ushort4 v0 = *(const ushort4*)(Xb + (size_t)c * NN + pq * 4);
      ushort4 v1 = *(const ushort4*)(Xb + (size_t)(c + 1) * NN + pq * 4);
#pragma unroll
      for (int j = 0; j < 4; ++j) {
        unsigned int u = ((unsigned int)((&v1.x)[j]) << 16) | (unsigned int)((&v0.x)[j]);
        *(unsigned int*)(&Xs[(pq * 4 + j) * LDP + c]) = u;
      }
    }
  }
  __syncthreads();
  int lane = tid & 63, w = tid >> 6;
  int wm = w & 1, wn = w >> 1;        // wave -> 32d x 64p quadrant
  int lrow = lane & 15, lq = lane >> 4;
  // preload this wave's B-frags for all 6 k-steps (reused 9x)
  short8 bf[6][4];
#pragma unroll
  for (int ks = 0; ks < 6; ++ks)
    for (int nt = 0; nt < 4; ++nt)
      bf[ks][nt] = *(const short8*)(&Xs[(wn * 64 + nt * 16 + lrow) * LDP + ks * 32 + lq * 8]);
  for (int dt = 0; dt < 9; ++dt) {    // 9 d-tiles of 64 over 576 rows
    int d0 = dt * 64;
    f32x4 acc[2][4];
    for (int mt = 0; mt < 2; ++mt)
      for (int nt = 0; nt < 4; ++nt) acc[mt][nt] = (f32x4){0.f, 0.f, 0.f, 0.f};
    for (int ks = 0; ks < 6; ++ks) {
      int k = ks * 32 + lq * 8;
      short8 a[2];
      for (int mt = 0; mt < 2; ++mt)
        a[mt] = *(const short8*)(Wall + (size_t)(d0 + wm * 32 + mt * 16 + lrow) * NC + k);
      for (int mt = 0; mt < 2; ++mt)
        for (int nt = 0; nt < 4; ++nt)
          acc[mt][nt] = __builtin_amdgcn_mfma_f32_16x16x32_bf16(a[mt], bf[ks][nt], acc[mt][nt], 0, 0, 0);
    }
    int proj = dt / 3, c0 = (dt % 3) * 64;
    unsigned short* Yb = Yall + (((size_t)proj * NB + b) * NC) * NN;
    for (int mt = 0; mt < 2; ++mt)
      for (int nt = 0; nt < 4; ++nt)
        for (int r = 0; r < 4; ++r) {
          int c = c0 + wm * 32 + mt * 16 + lq * 4 + r;
          int p = p0 + wn * 64 + nt * 16 + lrow;
          Yb[(size_t)c * NN + p] = f2bf(acc[mt][nt][r]);
        }
  }
}

// ------------------------------------------------------------ fused dwconv3x3 (+ sumsq)
// Deep-prefetch, LDS-free, shfl-free. One block = one (proj,b,c) 128x128 image.
// Thread: 8-col chunk (ch) x 8-row group (rg). All 10 input rows (8 + 2 halo)
// issued as one raw-bf16 load burst at entry (one latency exposure per wave);
// halo columns come from direct 2B edge loads (same cache lines as the
// neighbor lanes' short8 -> L1 hits, no ds/shfl dependency chain).
__device__ inline void cvtrow(short8 raw, unsigned short lo, unsigned short hi,
                              float* dst) {
  dst[0] = bf2f(lo);
#pragma unroll
  for (int j = 0; j < 8; ++j) dst[j + 1] = bf2f((unsigned short)raw[j]);
  dst[9] = bf2f(hi);
}

__global__ __launch_bounds__(256) void k_dwconv(const unsigned short* __restrict__ Yall,
                                                const unsigned short* __restrict__ Wdall,
                                                unsigned short* __restrict__ Pq,
                                                unsigned short* __restrict__ Pk,
                                                unsigned short* __restrict__ Pv,
                                                float* __restrict__ ssq,
                                                float* __restrict__ ssk) {
  int y = blockIdx.x, b = blockIdx.y;
  int proj = y / NC, c = y % NC;
  int tid = threadIdx.x;
  int lane = tid & 63, ch = tid & 15, rg = tid >> 4;
  const unsigned short* base = Yall + (((size_t)proj * NB + b) * NC + c) * NN;
  unsigned short* P = (proj == 0 ? Pq : (proj == 1 ? Pk : Pv));
  float* ss = (proj == 0 ? ssq : (proj == 1 ? ssk : nullptr));
  int r0 = rg * 8;

  // ---- prefetch burst: all 10 raw rows (r0-1 .. r0+8), 30 loads in flight.
  short8 raw[10];
  unsigned short hl[10], hr[10];
#pragma unroll
  for (int i = 0; i < 10; ++i) {
    int gy = r0 - 1 + i;
    const unsigned short* rp = base + gy * 128 + ch * 8;
    if (gy >= 0 && gy < 128) {
      raw[i] = *(const short8*)rp;
      hl[i] = (ch > 0)  ? rp[-1] : (unsigned short)0;
      hr[i] = (ch < 15) ? rp[8]  : (unsigned short)0;
    } else {
      raw[i] = (short8){0, 0, 0, 0, 0, 0, 0, 0};
      hl[i] = 0;
      hr[i] = 0;
    }
  }

  float wk9[9];
#pragma unroll
  for (int i = 0; i < 9; ++i) wk9[i] = bf2f(Wdall[(proj * NC + c) * 9 + i]);

  float rows[3][10];   // rows[i%3] holds extended input row (r0-1+i)
  cvtrow(raw[0], hl[0], hr[0], rows[0]);
  cvtrow(raw[1], hl[1], hr[1], rows[1]);
  float ssacc = 0.f;
#pragma unroll
  for (int r = 0; r < 8; ++r) {
    cvtrow(raw[r + 2], hl[r + 2], hr[r + 2], rows[(r + 2) % 3]);
    float z[8];
#pragma unroll
    for (int j = 0; j < 8; ++j) z[j] = 0.f;
#pragma unroll
    for (int dy = 0; dy < 3; ++dy) {
      const float* f = rows[(r + dy) % 3];
      float w0 = wk9[dy * 3], w1 = wk9[dy * 3 + 1], w2 = wk9[dy * 3 + 2];
#pragma unroll
      for (int j = 0; j < 8; ++j) z[j] += w0 * f[j] + w1 * f[j + 1] + w2 * f[j + 2];
    }
    short8 sv;
#pragma unroll
    for (int j = 0; j < 8; ++j) { sv[j] = (short)f2bf(z[j]); ssacc += z[j] * z[j]; }
    *(short8*)(P + ((size_t)b * NC + c) * NN + (r0 + r) * 128 + ch * 8) = sv;
  }
  if (ss) {
    for (int off = 32; off; off >>= 1) ssacc += __shfl_down(ssacc, off);
    if (lane == 0) atomicAdd(&ss[b * NC + c], ssacc);
  }
}

// ------------------------------------------------------------ S = Q.K^T
__global__ __launch_bounds__(256) void k_attn(const unsigned short* __restrict__ Qp,
                                              const unsigned short* __restrict__ Kp,
                                              float* __restrict__ S) {
  __shared__ float Sred[CH * CH];
  int bh = blockIdx.y, chunk = blockIdx.x;
  int b = bh >> 2, h = bh & 3;
  int tid = threadIdx.x, lane = tid & 63, w = tid >> 6;
  int lrow = lane & 15, lq = lane >> 4;
  const unsigned short* Qb = Qp + ((size_t)b * NC + h * CH) * NN;
  const unsigned short* Kb = Kp + ((size_t)b * NC + h * CH) * NN;
  int nbase = chunk * 1024 + w * 256;
  f32x4 acc[3][3];
  for (int i = 0; i < 3; ++i)
    for (int j = 0; j < 3; ++j) acc[i][j] = (f32x4){0.f, 0.f, 0.f, 0.f};
  for (int ks = 0; ks < 8; ++ks) {
    int n = nbase + ks * 32 + lq * 8;
    short8 a[3], bb[3];
    for (int t = 0; t < 3; ++t) a[t]  = *(const short8*)(Qb + (size_t)(t * 16 + lrow) * NN + n);
    for (int t = 0; t < 3; ++t) bb[t] = *(const short8*)(Kb + (size_t)(t * 16 + lrow) * NN + n);
    for (int ti = 0; ti < 3; ++ti)
      for (int tj = 0; tj < 3; ++tj)
        acc[ti][tj] = __builtin_amdgcn_mfma_f32_16x16x32_bf16(a[ti], bb[tj], acc[ti][tj], 0, 0, 0);
  }
  for (int i = tid; i < CH * CH; i += 256) Sred[i] = 0.f;
  __syncthreads();
  for (int ti = 0; ti < 3; ++ti)
    for (int tj = 0; tj < 3; ++tj)
      for (int r = 0; r < 4; ++r) {
        int row = ti * 16 + lq * 4 + r, col = tj * 16 + lrow;
        atomicAdd(&Sred[row * CH + col], acc[ti][tj][r]);
      }
  __syncthreads();
  float* Sg = S + bh * (CH * CH);
  for (int i = tid; i < CH * CH; i += 256) atomicAdd(&Sg[i], Sred[i]);
}

// ------------------------------------------------------------ softmax (+ norms)
__global__ void k_softmax(const float* __restrict__ S, const float* __restrict__ ssq,
                          const float* __restrict__ ssk, const unsigned short* __restrict__ tempc,
                          float* __restrict__ AT) {   // AT[bh][j][i]
  int bh = blockIdx.x, b = bh >> 2, h = bh & 3;
  int i = threadIdx.x;
  if (i >= CH) return;
  float t = bf2f(tempc[h]);
  float rq = 1.f / fmaxf(sqrtf(ssq[b * NC + h * CH + i]), 1e-12f);
  const float* Srow = S + bh * (CH * CH) + i * CH;
  float l[CH];
  float m = -1e30f;
  for (int j = 0; j < CH; ++j) {
    float rk = 1.f / fmaxf(sqrtf(ssk[b * NC + h * CH + j]), 1e-12f);
    l[j] = Srow[j] * rq * rk * t;
    m = fmaxf(m, l[j]);
  }
  float s = 0.f;
  for (int j = 0; j < CH; ++j) { l[j] = __expf(l[j] - m); s += l[j]; }
  float inv = 1.f / s;
  for (int j = 0; j < CH; ++j) AT[bh * (CH * CH) + j * CH + i] = l[j] * inv;
}

// ------------------------------------------------------------ out = attn . V
__global__ __launch_bounds__(256) void k_out(const float* __restrict__ AT,
                                             const unsigned short* __restrict__ Vp,
                                             void* __restrict__ Out,
                                             const unsigned short* __restrict__ x) {
  bool f32 = detect_f32(x);
  int bh = blockIdx.y, b = bh >> 2, h = bh & 3;
  int p0 = (blockIdx.x * 256 + threadIdx.x) * 2;
  const float* A = AT + bh * (CH * CH);            // [j][i], block-uniform
  const unsigned short* Vb = Vp + ((size_t)b * NC + h * CH) * NN;
  float a1[CH], a2[CH];
  for (int i = 0; i < CH; ++i) { a1[i] = 0.f; a2[i] = 0.f; }
  for (int j = 0; j < CH; ++j) {
    unsigned int u = *(const unsigned int*)(Vb + (size_t)j * NN + p0);
    float v1 = bf2f((unsigned short)(u & 0xFFFF));
    float v2 = bf2f((unsigned short)(u >> 16));
    const float* Aj = A + j * CH;
    for (int i = 0; i < CH; ++i) {
      float a = Aj[i];
      a1[i] += a * v1;
      a2[i] += a * v2;
    }
  }
  size_t obase = ((size_t)b * NC + h * CH) * NN;
  if (f32) {
    float* Of = (float*)Out;
    for (int i = 0; i < CH; ++i)
      *(float2*)(Of + obase + (size_t)i * NN + p0) = make_float2(a1[i], a2[i]);
  } else {
    unsigned short* Ob = (unsigned short*)Out;
    for (int i = 0; i < CH; ++i) {
      unsigned int u = ((unsigned int)f2bf(a2[i]) << 16) | f2bf(a1[i]);
      *(unsigned int*)(Ob + obase + (size_t)i * NN + p0) = u;
    }
  }
}

// ------------------------------------------------------------ launch
extern "C" void kernel_launch(void* const* d_in, const int* in_sizes, int n_in,
                              void* d_out, int out_size, void* d_ws, size_t ws_size,
                              hipStream_t stream) {
  const unsigned short* x = (const unsigned short*)d_in[0];

  const size_t TEN = (size_t)NB * NC * NN;   // 12,582,912 elems
  unsigned short* bufA = (unsigned short*)d_ws;   // Q'
  unsigned short* bufB = bufA + TEN;              // K'
  unsigned short* bufV = bufB + TEN;              // V'
  unsigned short* Yall = bufV + TEN;              // 3 conv outputs (75.5 MB)
  float* ssq = (float*)(Yall + 3 * TEN);
  float* ssk = ssq + NB * NC;
  float* S   = ssk + NB * NC;
  float* AT  = S + 16 * CH * CH;
  unsigned short* canon = (unsigned short*)(AT + 16 * CH * CH);
  // ws total ~= 151 MB (< 268 MB)
  const unsigned short* Wall = canon;             // Wq|Wk|Wv = 576x192
  const unsigned short* Wdall = canon + 110592;   // wqd|wkd|wvd = 576x9
  const unsigned short* Tmp = canon + 115776;

  k_pre<<<453 + (NZERO + 255) / 256, 256, 0, stream>>>(
      x, d_in[1], d_in[3], d_in[5], d_in[2], d_in[4], d_in[6], d_in[7], canon, ssq);
  k_conv<<<dim3(NN / 128, NB), 256, 0, stream>>>(Wall, x, Yall);
  k_dwconv<<<dim3(3 * NC, NB), 256, 0, stream>>>(Yall, Wdall, bufA, bufB, bufV, ssq, ssk);
  k_attn<<<dim3(16, 16), 256, 0, stream>>>(bufA, bufB, S);
  k_softmax<<<16, 64, 0, stream>>>(S, ssq, ssk, Tmp, AT);
  k_out<<<dim3(NN / 512, 16), 256, 0, stream>>>(AT, bufV, d_out, x);
}